// Round 1
// baseline (112.196 us; speedup 1.0000x reference)
//
#include <hip/hip_runtime.h>
#include <hip/hip_bf16.h>
#include <stdint.h>

typedef __bf16 bf16_t;
typedef __bf16 bf16x8 __attribute__((ext_vector_type(8)));
typedef float  f32x4  __attribute__((ext_vector_type(4)));

#define MFMA16(a, b, c) __builtin_amdgcn_mfma_f32_16x16x32_bf16((a), (b), (c), 0, 0, 0)
#define NINF (-__builtin_inff())

constexpr int NB = 16;      // batches
constexpr int LQ = 8192;
constexpr int LK = 128;
constexpr int H  = 128;
constexpr int QT = 128;     // q rows per block

// log2(e) / sqrt(H): fold softmax scale + exp2 conversion into one multiply
constexpr float C1 = 1.4426950408889634f / 11.313708498984761f;

// workspace layout (bytes)
constexpr size_t WS_FLAG = 0;
constexpr size_t WS_WQ   = 1024;                               // 128x128 bf16
constexpr size_t WS_K    = WS_WQ + (size_t)H * H * 2;          // 16 x 128x128 bf16
constexpr size_t WS_V    = WS_K + (size_t)NB * LK * H * 2;     // 16 x 128x128 bf16

// XOR swizzle for [128][128] bf16 LDS tiles (row stride 256 B):
// spreads the 16-byte column slots across banks per 8-row stripe.
__device__ __forceinline__ unsigned swz(unsigned row, unsigned byte) {
  return row * 256u + (byte ^ ((row & 7u) << 4));
}

// load 8 consecutive f32 and round-to-nearest-even into a bf16x8 fragment
__device__ __forceinline__ bf16x8 cvt_frag(const float* p) {
  f32x4 u0 = *(const f32x4*)p;
  f32x4 u1 = *(const f32x4*)(p + 4);
  bf16x8 v;
  #pragma unroll
  for (int e = 0; e < 4; ++e) { v[e] = (bf16_t)u0[e]; v[e + 4] = (bf16_t)u1[e]; }
  return v;
}

// ---------------------------------------------------------------------------
// Prep: blocks 0..15  -> K_b = x2_b @ wk^T, V_b = x2_b @ wv^T  (bf16 to ws)
//       block 16      -> wq -> bf16; mask dtype detection
// ---------------------------------------------------------------------------
__global__ __launch_bounds__(512) void prep_kernel(
    const float* __restrict__ x2, const float* __restrict__ wq,
    const float* __restrict__ wk, const float* __restrict__ wv,
    const unsigned* __restrict__ x3w, uint8_t* __restrict__ ws)
{
  const int tid = threadIdx.x;
  const int blk = blockIdx.x;

  if (blk == NB) {
    // (a) convert wq (128x128 f32) -> bf16 in ws
    const float* s = wq + tid * 32;
    bf16_t* d = (bf16_t*)(ws + WS_WQ) + tid * 32;
    #pragma unroll
    for (int j = 0; j < 4; ++j)
      *(bf16x8*)(d + j * 8) = cvt_frag(s + j * 8);

    // (b) mask dtype probe over first 2048 words of x3.
    // int32 bool: words in {0,1}. uint8 bool: bytes in {0,1} -> words like
    // 0x01010101 (>1). f32 bool: words in {0, 0x3f800000}.
    __shared__ int sF32, sBig;
    if (tid == 0) { sF32 = 0; sBig = 0; }
    __syncthreads();
    int f = 0, g = 0;
    #pragma unroll
    for (int j = 0; j < 4; ++j) {
      unsigned v = x3w[tid * 4 + j];
      if (v == 0x3f800000u) f = 1;
      else if (v > 1u) g = 1;
    }
    if (f) sF32 = 1;
    if (g) sBig = 1;
    __syncthreads();
    if (tid == 0) *(int*)(ws + WS_FLAG) = (sF32 == 0 && sBig == 1) ? 1 : 0;
    return;
  }

  // per-batch K/V GEMMs via MFMA (128x128x128 each)
  __shared__ uint8_t sX2[32768];
  {
    const int row = tid >> 2, seg = tid & 3;
    const float* s = x2 + (size_t)blk * LK * H + row * H + seg * 32;
    #pragma unroll
    for (int j = 0; j < 4; ++j)
      *(bf16x8*)(sX2 + swz(row, seg * 64 + j * 16)) = cvt_frag(s + j * 8);
  }
  __syncthreads();

  const int lane = tid & 63, w = tid >> 6;
  const int lo = lane & 15, hi = lane >> 4;

  bf16x8 a[4];
  #pragma unroll
  for (int kk = 0; kk < 4; ++kk)
    a[kk] = *(const bf16x8*)(sX2 + swz(16 * w + lo, kk * 64 + hi * 16));

  #pragma unroll
  for (int which = 0; which < 2; ++which) {
    const float* W = which ? wv : wk;
    bf16_t* D = (bf16_t*)(ws + (which ? WS_V : WS_K)) + (size_t)blk * LK * H;
    #pragma unroll
    for (int t = 0; t < 8; ++t) {
      f32x4 c = {0.f, 0.f, 0.f, 0.f};
      const float* wrow = W + (16 * t + lo) * H;
      #pragma unroll
      for (int kk = 0; kk < 4; ++kk)
        c = MFMA16(a[kk], cvt_frag(wrow + kk * 32 + hi * 8), c);
      #pragma unroll
      for (int r = 0; r < 4; ++r)
        D[(16 * w + hi * 4 + r) * H + 16 * t + lo] = (bf16_t)c[r];
    }
  }
}

// ---------------------------------------------------------------------------
// Main fused kernel: one block = (batch b, 128-row q tile).
// Per wave (16-row private band): Q = x1@wq^T -> S = Q@K^T -> masked softmax
// (in-register, shfl over 16-lane group) -> O' = P@V^T -> out[b][i][q].
// Only K + the wave-private Q/P band live in LDS (64 KB -> 2 blocks/CU).
// Single barrier (K staging); waves otherwise free-run.
// ---------------------------------------------------------------------------
__global__ __launch_bounds__(512, 4) void attn_kernel(
    const float* __restrict__ x1, const void* __restrict__ x3,
    const uint8_t* __restrict__ ws, float* __restrict__ out)
{
  __shared__ uint8_t sm[65536];
  uint8_t* sK  = sm;           // K_b, bf16, swizzled [128][128]
  uint8_t* sQP = sm + 32768;   // Q then P, bf16, swizzled [128][128]

  const int tid = threadIdx.x;
  const int blk = blockIdx.x;
  const int b   = blk >> 6;
  const int q0  = (blk & 63) * QT;

  const bf16_t* wsWQ = (const bf16_t*)(ws + WS_WQ);
  const bf16_t* wsK  = (const bf16_t*)(ws + WS_K) + (size_t)b * LK * H;
  const bf16_t* wsV  = (const bf16_t*)(ws + WS_V) + (size_t)b * LK * H;
  const int byteMode = *(const int*)(ws + WS_FLAG);

  // stage K_b into LDS (bf16 -> bf16, swizzled)
  {
    const int row = tid >> 2, seg = tid & 3;
    const bf16_t* s = wsK + row * H + seg * 32;
    #pragma unroll
    for (int j = 0; j < 4; ++j)
      *(bf16x8*)(sK + swz(row, seg * 64 + j * 16)) = *(const bf16x8*)(s + j * 8);
  }
  __syncthreads();

  const int lane = tid & 63, w = tid >> 6;
  const int lo = lane & 15, hi = lane >> 4;

  // ---- Phase Q: Q = X1_tile @ wq^T ----
  bf16x8 a[4];
  {
    const float* xr = x1 + ((size_t)b * LQ + q0 + 16 * w + lo) * H;
    #pragma unroll
    for (int kk = 0; kk < 4; ++kk)
      a[kk] = cvt_frag(xr + kk * 32 + hi * 8);
  }
  #pragma unroll
  for (int t = 0; t < 8; ++t) {
    f32x4 c = {0.f, 0.f, 0.f, 0.f};
    const bf16_t* wqr = wsWQ + (16 * t + lo) * H;
    #pragma unroll
    for (int kk = 0; kk < 4; ++kk)
      c = MFMA16(a[kk], *(const bf16x8*)(wqr + kk * 32 + hi * 8), c);
    // write Q band to LDS (C/D layout: row = 16w + hi*4 + r, col = 16t + lo)
    #pragma unroll
    for (int r = 0; r < 4; ++r)
      *(bf16_t*)(sQP + swz(16 * w + hi * 4 + r, (16 * t + lo) * 2)) = (bf16_t)c[r];
  }

  // ---- Phase S: S = Q @ K^T, mask, softmax ----
  float mz[8][4];  // additive mask penalties (0 or -inf)
  {
    const size_t mrow0 = ((size_t)b * LQ + q0 + 16 * w + hi * 4) * (size_t)LK + lo;
    if (byteMode) {
      const uint8_t* mp = (const uint8_t*)x3;
      #pragma unroll
      for (int t = 0; t < 8; ++t)
        #pragma unroll
        for (int r = 0; r < 4; ++r)
          mz[t][r] = mp[mrow0 + (size_t)r * LK + t * 16] ? NINF : 0.0f;
    } else {
      const unsigned* mp = (const unsigned*)x3;
      #pragma unroll
      for (int t = 0; t < 8; ++t)
        #pragma unroll
        for (int r = 0; r < 4; ++r)
          mz[t][r] = mp[mrow0 + (size_t)r * LK + t * 16] ? NINF : 0.0f;
    }
  }
  #pragma unroll
  for (int kk = 0; kk < 4; ++kk)
    a[kk] = *(const bf16x8*)(sQP + swz(16 * w + lo, kk * 64 + hi * 16));

  f32x4 acc[8];
  #pragma unroll
  for (int t = 0; t < 8; ++t) {
    f32x4 c = {0.f, 0.f, 0.f, 0.f};
    #pragma unroll
    for (int kk = 0; kk < 4; ++kk)
      c = MFMA16(a[kk], *(const bf16x8*)(sK + swz(16 * t + lo, kk * 64 + hi * 16)), c);
    acc[t] = c;
  }

  // row softmax: row (16w + hi*4 + r) is spread over the 16 lanes (lo) x 8 tiles
  float drow[4];
  #pragma unroll
  for (int r = 0; r < 4; ++r) {
    float m = NINF;
    #pragma unroll
    for (int t = 0; t < 8; ++t) {
      float z = acc[t][r] * C1 + mz[t][r];
      acc[t][r] = z;
      m = fmaxf(m, z);
    }
    #pragma unroll
    for (int off = 1; off < 16; off <<= 1)
      m = fmaxf(m, __shfl_xor(m, off));
    float dsum = 0.f;
    #pragma unroll
    for (int t = 0; t < 8; ++t) {
      float p = exp2f(acc[t][r] - m);
      acc[t][r] = p;
      dsum += p;
    }
    #pragma unroll
    for (int off = 1; off < 16; off <<= 1)
      dsum += __shfl_xor(dsum, off);
    drow[r] = 1.0f / dsum;
  }

  // write normalized P over the (now dead) Q band — same wave-private rows
  #pragma unroll
  for (int t = 0; t < 8; ++t)
    #pragma unroll
    for (int r = 0; r < 4; ++r)
      *(bf16_t*)(sQP + swz(16 * w + hi * 4 + r, (16 * t + lo) * 2)) =
          (bf16_t)(acc[t][r] * drow[r]);

  // ---- Phase O: O'[q][i] = sum_j P[q][j] * V[i][j]  (= out[b][i][q]) ----
  #pragma unroll
  for (int kk = 0; kk < 4; ++kk)
    a[kk] = *(const bf16x8*)(sQP + swz(16 * w + lo, kk * 64 + hi * 16));

  #pragma unroll
  for (int t = 0; t < 8; ++t) {
    f32x4 c = {0.f, 0.f, 0.f, 0.f};
    const bf16_t* vr = wsV + (16 * t + lo) * H;
    #pragma unroll
    for (int kk = 0; kk < 4; ++kk)
      c = MFMA16(a[kk], *(const bf16x8*)(vr + kk * 32 + hi * 8), c);
    // c[r] = out[b][16t+lo][q0 + 16w + hi*4 + r]: 4 consecutive q -> float4
    float* orow = out + ((size_t)b * LK + 16 * t + lo) * LQ + q0 + 16 * w + hi * 4;
    *(f32x4*)orow = c;
  }
}

extern "C" void kernel_launch(void* const* d_in, const int* in_sizes, int n_in,
                              void* d_out, int out_size, void* d_ws, size_t ws_size,
                              hipStream_t stream) {
  const float* x1 = (const float*)d_in[0];
  const float* x2 = (const float*)d_in[1];
  const void*  x3 = d_in[2];
  const float* wq = (const float*)d_in[3];
  const float* wk = (const float*)d_in[4];
  const float* wv = (const float*)d_in[5];
  uint8_t* ws = (uint8_t*)d_ws;
  float* out = (float*)d_out;

  prep_kernel<<<NB + 1, 512, 0, stream>>>(x2, wq, wk, wv, (const unsigned*)x3, ws);
  attn_kernel<<<NB * (LQ / QT), 512, 0, stream>>>(x1, x3, ws, out);
}